// Round 10
// baseline (158.479 us; speedup 1.0000x reference)
//
#include <hip/hip_runtime.h>

#define T_TOK 32768   // B*S
#define NQ    8
#define FFN   2048
#define EMB   512
#define BM    128
#define BN    256
#define BKB   64            // k per barrier period (2 x 32-k sub-chunks)
#define NSUPER (FFN / BKB)  // 32 periods

typedef __attribute__((ext_vector_type(8)))  short short8;
typedef __attribute__((ext_vector_type(16))) float f32x16;
typedef __attribute__((ext_vector_type(2)))  unsigned int u32x2;

__device__ __forceinline__ unsigned short f2bf(float f) {
  unsigned int u = __float_as_uint(f);
  u += 0x7fffu + ((u >> 16) & 1u);
  return (unsigned short)(u >> 16);
}

__device__ __forceinline__ unsigned pk2bf(float lo, float hi) {
#if __has_builtin(__builtin_amdgcn_cvt_pk_bf16_f32)
  typedef __attribute__((ext_vector_type(2))) __bf16 bf2;
  bf2 p = __builtin_amdgcn_cvt_pk_bf16_f32(lo, hi);
  return *(unsigned*)&p;
#else
  return (unsigned)f2bf(lo) | ((unsigned)f2bf(hi) << 16);
#endif
}

// ---------------------------------------------------------------------------
// prep_all: W2[FFN][EMB] fp32 -> w2t[EMB][FFN] bf16 (tiled transpose), plus
//   w1t16[f][16]: k<8 = W1[k][f], k==8 = b1[f] (bias folded as extra input
//   row; main kernel's bq supplies 1.0 there), k>8 = 0.   (R10/R11-verified)
// ---------------------------------------------------------------------------
__global__ void prep_all(const float* __restrict__ W1,
                         const float* __restrict__ b1,
                         const float* __restrict__ W2,
                         unsigned short* __restrict__ w1t,
                         unsigned short* __restrict__ w2t) {
  __shared__ float t[32][33];
  const int kb = blockIdx.x * 32;   // FFN tile
  const int nb = blockIdx.y * 32;   // EMB tile
  const int tid = threadIdx.x;
  const int c = tid & 31, r0 = tid >> 5;
#pragma unroll
  for (int p = 0; p < 4; ++p) {
    int r = r0 + p * 8;
    t[r][c] = W2[(size_t)(kb + r) * EMB + nb + c];
  }
  __syncthreads();
#pragma unroll
  for (int p = 0; p < 4; ++p) {
    int r = r0 + p * 8;
    w2t[(size_t)(nb + r) * FFN + kb + c] = f2bf(t[c][r]);
  }
  if (blockIdx.x == 0) {
    const int f     = blockIdx.y * 128 + (tid >> 1);
    const int khalf = tid & 1;
    unsigned short v8[8];
#pragma unroll
    for (int j = 0; j < 8; ++j) {
      const int k = khalf * 8 + j;
      float val = (k < 8) ? W1[(size_t)k * FFN + f]
                          : (k == 8 ? b1[f] : 0.f);
      v8[j] = f2bf(val);
    }
    *(uint4*)(w1t + (size_t)f * 16 + khalf * 8) = *(uint4*)v8;
  }
}

// ---------------------------------------------------------------------------
// Fused main, R12: R11 (BN=256, 2 blocks/CU) with HALVED period count.
//   R11 confirmed: wall = per-period fixed overhead x period count + pipe
//   work. This round: BKB=64 (2 sub-chunks per barrier), 32 periods,
//   32 GEMM2-MFMA + 2 gemm1 per period.
//   Register discipline (R8's spill lesson): af state stays at R11's 32
//   regs via rotation -- gemm1(sub1 of CURRENT period) at period START
//   (its result consumed after the 16 covering sub0-MFMAs), gemm1(sub0 of
//   NEXT period) at period END. All named regs, no runtime indexing.
//   LDS = 2 bufs x 2 subs x 16 KiB = 64 KiB -> 2 blocks/CU resident.
//   Spill tripwire: WRITE_SIZE must stay exactly 65536 KB; VGPR <= 128.
// ---------------------------------------------------------------------------
__global__ __launch_bounds__(256, 2) void ffq_main(
    const float* __restrict__ x,
    const float* __restrict__ theta,
    const unsigned short* __restrict__ w1t,
    const unsigned short* __restrict__ w2t,
    const float* __restrict__ b2,
    float* __restrict__ out) {

  __shared__ __align__(16) unsigned short w2_lds[2][2][BN * 32];  // 65536 B

  const int tid  = threadIdx.x;
  const int wave = tid >> 6;
  const int lane = tid & 63;
  const int nl   = lane & 31;
  const int hi   = lane >> 5;
  const int tok0 = blockIdx.x * BM;
  const int n0   = blockIdx.y * BN;

  // ---- bq: B[k=q][tok]; hi half selects the bias row (k=8 -> 1.0) ----
  float cth[8];
  {
    const float4* tp = (const float4*)theta;
    float4 t0 = tp[0], t1 = tp[1];
    cth[0] = __cosf(t0.x); cth[1] = __cosf(t0.y);
    cth[2] = __cosf(t0.z); cth[3] = __cosf(t0.w);
    cth[4] = __cosf(t1.x); cth[5] = __cosf(t1.y);
    cth[6] = __cosf(t1.z); cth[7] = __cosf(t1.w);
  }
  short8 bq;
  {
    const float4* xp =
        (const float4*)(x + (size_t)(tok0 + wave * 32 + nl) * NQ);
    float4 x0 = xp[0], x1 = xp[1];
    float q0 = __cosf(x0.x) * cth[0], q1 = __cosf(x0.y) * cth[1];
    float q2 = __cosf(x0.z) * cth[2], q3 = __cosf(x0.w) * cth[3];
    float q4 = __cosf(x1.x) * cth[4], q5 = __cosf(x1.y) * cth[5];
    float q6 = __cosf(x1.z) * cth[6], q7 = __cosf(x1.w) * cth[7];
    uint4 uu;
    uu.x = pk2bf(q0, q1); uu.y = pk2bf(q2, q3);
    uu.z = pk2bf(q4, q5); uu.w = pk2bf(q6, q7);
    if (hi) { uu.x = 0x00003f80u; uu.y = 0; uu.z = 0; uu.w = 0; }  // k=8: 1.0
    bq = *(short8*)&uu;
  }

  // ---- w2 staging: linear LDS dest, pre-swizzled global source ----
  // Per sub: stored 16B-chunk c of row r holds global chunk c ^ ((r>>1)&3);
  // r = issue*64 + (tid>>2), c = tid&3  ->  gc = (tid&3) ^ ((tid>>3)&3).
  const int st_gc = (tid & 3) ^ ((tid >> 3) & 3);
  auto stage_super = [&](int sc_, int b_) {
    const int k0_ = sc_ * BKB;
#pragma unroll
    for (int sub = 0; sub < 2; ++sub) {
#pragma unroll
      for (int issue = 0; issue < 4; ++issue) {
        const int r = issue * 64 + (tid >> 2);
        __builtin_amdgcn_global_load_lds(
            (const __attribute__((address_space(1))) void*)(
                w2t + (size_t)(n0 + r) * FFN + k0_ + sub * 32 + st_gc * 8),
            (__attribute__((address_space(3))) void*)(
                &w2_lds[b_][sub][issue * 2048 + tid * 8]),
            16, 0, 0);
      }
    }
  };

  // ---- GEMM2 B-frag read offsets (de-swizzle; nt-independent) ----
  const int swz  = (nl >> 1) & 3;
  const int off0 = nl * 32 + ((0 + hi) ^ swz) * 8;   // ks=0
  const int off1 = nl * 32 + ((2 + hi) ^ swz) * 8;   // ks=1

  f32x16 acc[8];
#pragma unroll
  for (int nt = 0; nt < 8; ++nt)
#pragma unroll
    for (int r = 0; r < 16; ++r) acc[nt][r] = 0.f;

  // ---- GEMM1 -> A-frags (R7/R10/R11-verified permlane routing) ----
  auto gemm1 = [&](short8 aw, short8& oA, short8& oB) {
    f32x16 c1;
#pragma unroll
    for (int r = 0; r < 16; ++r) c1[r] = 0.f;
    c1 = __builtin_amdgcn_mfma_f32_32x32x16_bf16(aw, bq, c1, 0, 0, 0);
    unsigned Q[8];
#pragma unroll
    for (int p = 0; p < 8; ++p) {
      float lo = c1[2 * p]     > 0.f ? c1[2 * p]     : 0.f;
      float hl = c1[2 * p + 1] > 0.f ? c1[2 * p + 1] : 0.f;
      Q[p] = pk2bf(lo, hl);
    }
    u32x2 s0 = __builtin_amdgcn_permlane32_swap(Q[0], Q[2], false, false);
    u32x2 s1 = __builtin_amdgcn_permlane32_swap(Q[1], Q[3], false, false);
    u32x2 s2 = __builtin_amdgcn_permlane32_swap(Q[4], Q[6], false, false);
    u32x2 s3 = __builtin_amdgcn_permlane32_swap(Q[5], Q[7], false, false);
    uint4 uA; uA.x = s0[0]; uA.y = s1[0]; uA.z = s0[1]; uA.w = s1[1];
    uint4 uB; uB.x = s2[0]; uB.y = s3[0]; uB.z = s2[1]; uB.w = s3[1];
    oA = *(short8*)&uA;
    oB = *(short8*)&uB;
  };

  // GEMM2 inner: 8 col-tiles for one sub-chunk, one ks half
  auto gemm2_half = [&](const unsigned short* sb, int off, short8 af) {
#pragma unroll
    for (int nt = 0; nt < 8; ++nt) {
      short8 bf = *(const short8*)(sb + off + nt * 1024);
      acc[nt] = __builtin_amdgcn_mfma_f32_32x32x16_bf16(af, bf, acc[nt],
                                                        0, 0, 0);
    }
  };

  // ---- prologue: stage super 0; gemm1(sub0 of period 0) ----
  short8 afA0, afB0, afA1, afB1;
  {
    stage_super(0, 0);
    short8 aw = *(const short8*)(w1t + (size_t)nl * 16 + hi * 8);
    gemm1(aw, afA0, afB0);
  }

#pragma unroll 2
  for (int kc = 0; kc < NSUPER; ++kc) {
    const int b  = kc & 1;
    const int nc = (kc + 1 < NSUPER) ? kc + 1 : NSUPER - 1;  // clamp: uniform

    // stage(kc) had a full 32-MFMA body to land -> near-free drain
    asm volatile("s_waitcnt vmcnt(0)" ::: "memory");
    __builtin_amdgcn_s_barrier();   // super[b] ready; readers of [b^1] done
    __builtin_amdgcn_sched_barrier(0);

    // aw for sub1 of THIS period (consumed by gemm1 just below)
    short8 aw1 =
        *(const short8*)(w1t + (size_t)(kc * BKB + 32 + nl) * 16 + hi * 8);

    stage_super(nc, b ^ 1);         // prefetch next super (stays in flight)

    // gemm1(sub1 current): result consumed after 16 covering MFMAs
    gemm1(aw1, afA1, afB1);

    // ---- GEMM2 sub0 (af from end of previous period) ----
    const unsigned short* sb0 = &w2_lds[b][0][0];
    gemm2_half(sb0, off0, afA0);
    gemm2_half(sb0, off1, afB0);

    // ---- GEMM2 sub1 (af computed at period start) ----
    const unsigned short* sb1 = &w2_lds[b][1][0];
    gemm2_half(sb1, off0, afA1);
    gemm2_half(sb1, off1, afB1);

    // gemm1(sub0 of NEXT period): VALU hides under the MFMA cluster above
    short8 aw0 =
        *(const short8*)(w1t + (size_t)(nc * BKB + nl) * 16 + hi * 8);
    gemm1(aw0, afA0, afB0);
  }

  // drain the clamped last prefetch before LDS goes away
  asm volatile("s_waitcnt vmcnt(0)" ::: "memory");

  // ---- epilogue: + b2, fp32 store ----
#pragma unroll
  for (int nt = 0; nt < 8; ++nt) {
    const int col = n0 + nt * 32 + nl;
    const float bv = b2[col];
    const int rbase = tok0 + wave * 32 + 4 * hi;
#pragma unroll
    for (int g2 = 0; g2 < 4; ++g2)
#pragma unroll
      for (int rr = 0; rr < 4; ++rr)
        out[(size_t)(rbase + 8 * g2 + rr) * EMB + col] =
            acc[nt][4 * g2 + rr] + bv;
  }
}

extern "C" void kernel_launch(void* const* d_in, const int* in_sizes, int n_in,
                              void* d_out, int out_size, void* d_ws, size_t ws_size,
                              hipStream_t stream) {
  const float* x     = (const float*)d_in[0];
  const float* theta = (const float*)d_in[1];
  const float* W1    = (const float*)d_in[2];
  const float* b1    = (const float*)d_in[3];
  const float* W2    = (const float*)d_in[4];
  const float* b2    = (const float*)d_in[5];
  float* out = (float*)d_out;

  unsigned short* w1t = (unsigned short*)d_ws;       // FFN*16 = 32768 bf16
  unsigned short* w2t = w1t + FFN * 16;              // 1048576 bf16 [EMB][FFN]

  prep_all<<<dim3(FFN / 32, EMB / 32), 256, 0, stream>>>(W1, b1, W2, w1t, w2t);

  dim3 grid(T_TOK / BM, EMB / BN);  // (256, 2) = 512 blocks = 2/CU
  ffq_main<<<grid, 256, 0, stream>>>(x, theta, w1t, w2t, b2, out);
}